// Round 2
// baseline (1051.569 us; speedup 1.0000x reference)
//
#include <hip/hip_runtime.h>
#include <hip/hip_bf16.h>
#include <math.h>

#define B_   4
#define T_   2048
#define C_   2048
#define NH_  16
#define HD_  128
#define KVD_ 1024

typedef __attribute__((ext_vector_type(4))) float f32x4;
typedef __attribute__((ext_vector_type(8))) short bf16x8;

__device__ __forceinline__ void async_copy16(const __hip_bfloat16* g, __hip_bfloat16* l) {
  __builtin_amdgcn_global_load_lds((const __attribute__((address_space(1))) void*)g,
                                   (__attribute__((address_space(3))) void*)l,
                                   16, 0, 0);
}

__device__ __forceinline__ float bf2f(__hip_bfloat16 h) { return __bfloat162float(h); }

// ---------------- f32 -> bf16 convert (x) ----------------
__global__ __launch_bounds__(256) void f32_to_bf16_k(const float* __restrict__ src,
                                                     __hip_bfloat16* __restrict__ dst, int n4) {
  int i = blockIdx.x * 256 + threadIdx.x;
  if (i >= n4) return;
  float4 f = ((const float4*)src)[i];
  __hip_bfloat16 o[4] = {__float2bfloat16(f.x), __float2bfloat16(f.y),
                         __float2bfloat16(f.z), __float2bfloat16(f.w)};
  *(uint2*)(dst + (size_t)i * 4) = *(uint2*)o;
}

// ---------------- transpose + convert: WT[n][k] = bf16(W[k][n]) ----------------
__global__ __launch_bounds__(256) void transpose_f32_bf16_k(const float* __restrict__ W,
                                                            __hip_bfloat16* __restrict__ WT,
                                                            int K, int N) {
  __shared__ float tile[32][33];
  int bx = blockIdx.x * 32;  // n
  int by = blockIdx.y * 32;  // k
  int tx = threadIdx.x, ty = threadIdx.y;
  for (int i = ty; i < 32; i += 8)
    tile[i][tx] = W[(size_t)(by + i) * N + (bx + tx)];
  __syncthreads();
  for (int i = ty; i < 32; i += 8)
    WT[(size_t)(bx + i) * K + (by + tx)] = __float2bfloat16(tile[tx][i]);
}

// ---------------- row l2norm (in place, bf16), scale folded via `extra` ----------------
template<int PER>
__global__ __launch_bounds__(256) void rownorm_k(__hip_bfloat16* __restrict__ buf,
                                                 int stride, float extra) {
  const int tid = threadIdx.x;
  __hip_bfloat16* p = buf + (size_t)blockIdx.x * stride;
  float v[PER];
  float ss = 0.f;
  #pragma unroll
  for (int e = 0; e < PER; ++e) { v[e] = bf2f(p[tid + e * 256]); ss += v[e] * v[e]; }
  #pragma unroll
  for (int off = 32; off >= 1; off >>= 1) ss += __shfl_xor(ss, off, 64);
  __shared__ float wsum[4];
  if ((tid & 63) == 0) wsum[tid >> 6] = ss;
  __syncthreads();
  float tot = wsum[0] + wsum[1] + wsum[2] + wsum[3];
  float sc = extra / (sqrtf(tot) + 1e-12f);
  #pragma unroll
  for (int e = 0; e < PER; ++e) p[tid + e * 256] = __float2bfloat16(v[e] * sc);
}

// ---------------- GEMM: C[M][N] = A[M][K] @ BT[N][K]^T, bf16 in, OutT out ----------------
// m97 structure: 128x128 tile, BK=32, global_load_lds width-16 staging.
template<typename OutT>
__global__ __launch_bounds__(256) void gemm_bt_k(const __hip_bfloat16* __restrict__ A,
                                                 const __hip_bfloat16* __restrict__ BT,
                                                 OutT* __restrict__ Cc,
                                                 int M, int N, int K) {
  __shared__ alignas(16) __hip_bfloat16 As[128 * 32];
  __shared__ alignas(16) __hip_bfloat16 Bs[128 * 32];
  const int tid = threadIdx.x;
  const int bm = blockIdx.y * 128;
  const int bn = blockIdx.x * 128;
  const int wave = tid >> 6, lane = tid & 63;
  const int wr = (wave >> 1) * 64, wc = (wave & 1) * 64;
  const int lm = lane & 15, lk = (lane >> 4) * 8;
  const size_t Kz = (size_t)K;
  const __hip_bfloat16* a0 = A + (size_t)(bm + (tid >> 2)) * Kz + (size_t)((tid & 3) * 8);
  const __hip_bfloat16* b0 = BT + (size_t)(bn + (tid >> 2)) * Kz + (size_t)((tid & 3) * 8);
  const __hip_bfloat16* a1 = a0 + 64 * Kz;
  const __hip_bfloat16* b1 = b0 + 64 * Kz;
  f32x4 acc[4][4] = {};
  for (int k0 = 0; k0 < K; k0 += 32) {
    async_copy16(a0 + k0, As + tid * 8);
    async_copy16(a1 + k0, As + 2048 + tid * 8);
    async_copy16(b0 + k0, Bs + tid * 8);
    async_copy16(b1 + k0, Bs + 2048 + tid * 8);
    __syncthreads();
    bf16x8 af[4], bfr[4];
    #pragma unroll
    for (int t = 0; t < 4; ++t) {
      af[t]  = *(const bf16x8*)(As + (wr + t * 16 + lm) * 32 + lk);
      bfr[t] = *(const bf16x8*)(Bs + (wc + t * 16 + lm) * 32 + lk);
    }
    #pragma unroll
    for (int mt = 0; mt < 4; ++mt)
      #pragma unroll
      for (int nt = 0; nt < 4; ++nt)
        acc[mt][nt] = __builtin_amdgcn_mfma_f32_16x16x32_bf16(af[mt], bfr[nt], acc[mt][nt], 0, 0, 0);
    __syncthreads();
  }
  const int r0 = (lane >> 4) * 4;
  #pragma unroll
  for (int mt = 0; mt < 4; ++mt)
    #pragma unroll
    for (int nt = 0; nt < 4; ++nt)
      #pragma unroll
      for (int r = 0; r < 4; ++r) {
        int gr = bm + wr + mt * 16 + r0 + r;
        int gc = bn + wc + nt * 16 + lm;
        float v = acc[mt][nt][r];
        if constexpr (__is_same(OutT, float))
          Cc[(size_t)gr * N + gc] = v;
        else
          Cc[(size_t)gr * N + gc] = __float2bfloat16(v);
      }
}

// ---------------- flash attention, MFMA QK^T and PV, online softmax ----------------
// grid (T/64, NH, B); block 256 (4 waves, 16 q-rows each).
// q: [B][T][C] bf16, l2-normed * 1/sqrt(HD).  kv: [B][T][1024]: [0:512] k (l2-normed), [512:1024] v.
__global__ __launch_bounds__(256) void attn_k(const __hip_bfloat16* __restrict__ q,
                                              const __hip_bfloat16* __restrict__ kv,
                                              __hip_bfloat16* __restrict__ y) {
  const int qt = blockIdx.x;
  const int h  = blockIdx.y;
  const int b  = blockIdx.z;
  const int g  = h >> 2;
  const int tid = threadIdx.x;
  const int wave = tid >> 6, lane = tid & 63;
  const int lm = lane & 15;
  const int quad = lane >> 4;
  const int lk = quad * 8;
  const int r0 = quad * 4;

  __shared__ alignas(16) __hip_bfloat16 Ks[64 * 128];
  __shared__ alignas(16) __hip_bfloat16 Vs[64 * 128];
  __shared__ alignas(16) __hip_bfloat16 Qs[64 * 128];  // reused per-wave as P after q-frag reads

  // stage Q tile (64x128)
  {
    const __hip_bfloat16* qb = q + ((size_t)b * T_ + (size_t)qt * 64) * C_ + h * HD_;
    #pragma unroll
    for (int e = 0; e < 4; ++e) {
      int c = tid + e * 256;
      async_copy16(qb + (size_t)(c >> 4) * C_ + (c & 15) * 8, Qs + c * 8);
    }
  }
  const __hip_bfloat16* kvb = kv + (size_t)b * T_ * KVD_ + g * HD_;
  // stage K/V tile 0 (each 64x128)
  #pragma unroll
  for (int e = 0; e < 4; ++e) {
    int c = tid + e * 256;
    const __hip_bfloat16* rowp = kvb + (size_t)(c >> 4) * KVD_ + (c & 15) * 8;
    async_copy16(rowp, Ks + c * 8);
    async_copy16(rowp + 512, Vs + c * 8);
  }
  __syncthreads();

  bf16x8 qf[4];
  #pragma unroll
  for (int kc = 0; kc < 4; ++kc)
    qf[kc] = *(const bf16x8*)(Qs + (wave * 16 + lm) * 128 + kc * 32 + lk);

  __hip_bfloat16* Psw = Qs + wave * 2048;  // wave-private [16][64], inside this wave's Q quarter

  float m_run[4] = {-1e30f, -1e30f, -1e30f, -1e30f};
  float l_run[4] = {0.f, 0.f, 0.f, 0.f};
  f32x4 o_acc[8] = {};

  const int ntiles = qt + 1;
  for (int it = 0; it < ntiles; ++it) {
    // S = Q K^T (scale pre-folded into q)
    f32x4 sv[4] = {};
    #pragma unroll
    for (int kc = 0; kc < 4; ++kc) {
      #pragma unroll
      for (int st = 0; st < 4; ++st) {
        bf16x8 kf = *(const bf16x8*)(Ks + (st * 16 + lm) * 128 + kc * 32 + lk);
        sv[st] = __builtin_amdgcn_mfma_f32_16x16x32_bf16(qf[kc], kf, sv[st], 0, 0, 0);
      }
    }
    const int j0 = it * 64;
    const int qg = qt * 64 + wave * 16 + r0;  // + r
    float mt_[4] = {-1e30f, -1e30f, -1e30f, -1e30f};
    #pragma unroll
    for (int st = 0; st < 4; ++st) {
      int sg = j0 + st * 16 + lm;
      #pragma unroll
      for (int r = 0; r < 4; ++r) {
        float s = sv[st][r];
        s = (sg > qg + r) ? -1e30f : s;
        sv[st][r] = s;
        mt_[r] = fmaxf(mt_[r], s);
      }
    }
    #pragma unroll
    for (int r = 0; r < 4; ++r) {
      #pragma unroll
      for (int off = 1; off <= 8; off <<= 1)
        mt_[r] = fmaxf(mt_[r], __shfl_xor(mt_[r], off, 64));
      float mn = fmaxf(m_run[r], mt_[r]);
      mt_[r] = __expf(m_run[r] - mn);  // alpha
      m_run[r] = mn;
    }
    float rs[4] = {0.f, 0.f, 0.f, 0.f};
    #pragma unroll
    for (int st = 0; st < 4; ++st)
      #pragma unroll
      for (int r = 0; r < 4; ++r) {
        float pv = __expf(sv[st][r] - m_run[r]);
        sv[st][r] = pv;
        rs[r] += pv;
      }
    #pragma unroll
    for (int r = 0; r < 4; ++r) {
      #pragma unroll
      for (int off = 1; off <= 8; off <<= 1)
        rs[r] += __shfl_xor(rs[r], off, 64);
      l_run[r] = l_run[r] * mt_[r] + rs[r];
    }
    #pragma unroll
    for (int nt = 0; nt < 8; ++nt)
      #pragma unroll
      for (int r = 0; r < 4; ++r)
        o_acc[nt][r] = o_acc[nt][r] * mt_[r];
    // write P (C-layout -> A-layout via wave-private LDS round trip)
    #pragma unroll
    for (int st = 0; st < 4; ++st)
      #pragma unroll
      for (int r = 0; r < 4; ++r)
        Psw[(r0 + r) * 64 + st * 16 + lm] = __float2bfloat16(sv[st][r]);
    __asm__ volatile("s_waitcnt lgkmcnt(0)" ::: "memory");
    // O += P V
    #pragma unroll
    for (int kc = 0; kc < 2; ++kc) {
      bf16x8 pf = *(const bf16x8*)(Psw + lm * 64 + kc * 32 + lk);
      #pragma unroll
      for (int nt = 0; nt < 8; ++nt) {
        bf16x8 vf;
        #pragma unroll
        for (int j = 0; j < 8; ++j)
          vf[j] = *(const short*)(Vs + (kc * 32 + lk + j) * 128 + nt * 16 + lm);
        o_acc[nt] = __builtin_amdgcn_mfma_f32_16x16x32_bf16(pf, vf, o_acc[nt], 0, 0, 0);
      }
    }
    __syncthreads();
    if (it + 1 < ntiles) {
      int j1 = (it + 1) * 64;
      #pragma unroll
      for (int e = 0; e < 4; ++e) {
        int c = tid + e * 256;
        const __hip_bfloat16* rowp = kvb + (size_t)(j1 + (c >> 4)) * KVD_ + (c & 15) * 8;
        async_copy16(rowp, Ks + c * 8);
        async_copy16(rowp + 512, Vs + c * 8);
      }
      __syncthreads();
    }
  }
  // epilogue: y[b][t][h*HD + d] = O / l
  #pragma unroll
  for (int nt = 0; nt < 8; ++nt)
    #pragma unroll
    for (int r = 0; r < 4; ++r) {
      int t = qt * 64 + wave * 16 + r0 + r;
      int d = nt * 16 + lm;
      float val = o_acc[nt][r] / l_run[r];
      y[((size_t)b * T_ + t) * C_ + h * HD_ + d] = __float2bfloat16(val);
    }
}

extern "C" void kernel_launch(void* const* d_in, const int* in_sizes, int n_in,
                              void* d_out, int out_size, void* d_ws, size_t ws_size,
                              hipStream_t stream) {
  (void)in_sizes; (void)n_in; (void)out_size; (void)ws_size;
  const float* x     = (const float*)d_in[0];
  const float* Wq    = (const float*)d_in[1];
  const float* Wkv   = (const float*)d_in[2];
  const float* Wproj = (const float*)d_in[3];
  char* ws = (char*)d_ws;
  // workspace layout (bytes):
  __hip_bfloat16* xb     = (__hip_bfloat16*)(ws);               // 32 MB  (reused as y later)
  __hip_bfloat16* WqT    = (__hip_bfloat16*)(ws + 33554432);    //  8 MB
  __hip_bfloat16* WkvT   = (__hip_bfloat16*)(ws + 41943040);    //  4 MB
  __hip_bfloat16* WprojT = (__hip_bfloat16*)(ws + 46137344);    //  8 MB
  __hip_bfloat16* qn     = (__hip_bfloat16*)(ws + 54525952);    // 32 MB
  __hip_bfloat16* kvb    = (__hip_bfloat16*)(ws + 88080384);    // 16 MB
  __hip_bfloat16* y      = xb;                                  // alias: xb dead after gemm2
  float* out             = (float*)d_out;  // reference output dtype is float32

  f32_to_bf16_k<<<16384, 256, 0, stream>>>(x, xb, 4194304);
  transpose_f32_bf16_k<<<dim3(64, 64), dim3(32, 8), 0, stream>>>(Wq, WqT, 2048, 2048);
  transpose_f32_bf16_k<<<dim3(32, 64), dim3(32, 8), 0, stream>>>(Wkv, WkvT, 2048, 1024);
  transpose_f32_bf16_k<<<dim3(64, 64), dim3(32, 8), 0, stream>>>(Wproj, WprojT, 2048, 2048);
  gemm_bt_k<__hip_bfloat16><<<dim3(16, 64), 256, 0, stream>>>(xb, WqT, qn, 8192, 2048, 2048);
  gemm_bt_k<__hip_bfloat16><<<dim3(8, 64), 256, 0, stream>>>(xb, WkvT, kvb, 8192, 1024, 2048);
  rownorm_k<8><<<8192, 256, 0, stream>>>(qn, 2048, 0.08838834764831845f);  // 1/sqrt(HD) folded
  rownorm_k<2><<<8192, 256, 0, stream>>>(kvb, 1024, 1.0f);
  attn_k<<<dim3(32, 16, 4), 256, 0, stream>>>(qn, kvb, y);
  gemm_bt_k<float><<<dim3(16, 64), 256, 0, stream>>>(y, WprojT, out, 8192, 2048, 2048);
}

// Round 3
// 764.275 us; speedup vs baseline: 1.3759x; 1.3759x over previous
//
#include <hip/hip_runtime.h>
#include <hip/hip_bf16.h>
#include <math.h>

#define B_   4
#define T_   2048
#define C_   2048
#define NH_  16
#define HD_  128
#define KVD_ 1024

typedef __attribute__((ext_vector_type(4))) float f32x4;
typedef __attribute__((ext_vector_type(8))) short bf16x8;

__device__ __forceinline__ void async_copy16(const __hip_bfloat16* g, __hip_bfloat16* l) {
  __builtin_amdgcn_global_load_lds((const __attribute__((address_space(1))) void*)g,
                                   (__attribute__((address_space(3))) void*)l,
                                   16, 0, 0);
}

__device__ __forceinline__ float bf2f(__hip_bfloat16 h) { return __bfloat162float(h); }

// ---------------- f32 -> bf16 convert (x) ----------------
__global__ __launch_bounds__(256) void f32_to_bf16_k(const float* __restrict__ src,
                                                     __hip_bfloat16* __restrict__ dst, int n4) {
  int i = blockIdx.x * 256 + threadIdx.x;
  if (i >= n4) return;
  float4 f = ((const float4*)src)[i];
  __hip_bfloat16 o[4] = {__float2bfloat16(f.x), __float2bfloat16(f.y),
                         __float2bfloat16(f.z), __float2bfloat16(f.w)};
  *(uint2*)(dst + (size_t)i * 4) = *(uint2*)o;
}

// ---------------- transpose + convert: WT[n][k] = bf16(W[k][n]) ----------------
__global__ __launch_bounds__(256) void transpose_f32_bf16_k(const float* __restrict__ W,
                                                            __hip_bfloat16* __restrict__ WT,
                                                            int K, int N) {
  __shared__ float tile[32][33];
  int bx = blockIdx.x * 32;  // n
  int by = blockIdx.y * 32;  // k
  int tx = threadIdx.x, ty = threadIdx.y;
  for (int i = ty; i < 32; i += 8)
    tile[i][tx] = W[(size_t)(by + i) * N + (bx + tx)];
  __syncthreads();
  for (int i = ty; i < 32; i += 8)
    WT[(size_t)(bx + i) * K + (by + tx)] = __float2bfloat16(tile[tx][i]);
}

// ---------------- V transpose: Vt[b][g][d][t] = kv[b][t][512 + g*128 + d] ----------------
__global__ __launch_bounds__(256) void vtrans_k(const __hip_bfloat16* __restrict__ kv,
                                                __hip_bfloat16* __restrict__ vt) {
  __shared__ __hip_bfloat16 tile[32][33];
  int bg = blockIdx.z;            // b*4+g
  int d0 = blockIdx.y * 32;
  int t0 = blockIdx.x * 32;
  int tx = threadIdx.x, ty = threadIdx.y;
  int b = bg >> 2, g = bg & 3;
  const __hip_bfloat16* src = kv + (size_t)b * T_ * KVD_ + 512 + g * HD_;
  for (int i = ty; i < 32; i += 8)
    tile[i][tx] = src[(size_t)(t0 + i) * KVD_ + d0 + tx];
  __syncthreads();
  __hip_bfloat16* dst = vt + (size_t)bg * HD_ * T_;
  for (int i = ty; i < 32; i += 8)
    dst[(size_t)(d0 + i) * T_ + t0 + tx] = tile[tx][i];
}

// ---------------- row l2norm (in place, bf16), scale folded via `extra` ----------------
template<int PER>
__global__ __launch_bounds__(256) void rownorm_k(__hip_bfloat16* __restrict__ buf,
                                                 int stride, float extra) {
  const int tid = threadIdx.x;
  __hip_bfloat16* p = buf + (size_t)blockIdx.x * stride;
  float v[PER];
  float ss = 0.f;
  #pragma unroll
  for (int e = 0; e < PER; ++e) { v[e] = bf2f(p[tid + e * 256]); ss += v[e] * v[e]; }
  #pragma unroll
  for (int off = 32; off >= 1; off >>= 1) ss += __shfl_xor(ss, off, 64);
  __shared__ float wsum[4];
  if ((tid & 63) == 0) wsum[tid >> 6] = ss;
  __syncthreads();
  float tot = wsum[0] + wsum[1] + wsum[2] + wsum[3];
  float sc = extra / (sqrtf(tot) + 1e-12f);
  #pragma unroll
  for (int e = 0; e < PER; ++e) p[tid + e * 256] = __float2bfloat16(v[e] * sc);
}

// ---------------- GEMM: C[M][N] = A[M][K] @ BT[N][K]^T, bf16 in, OutT out ----------------
template<typename OutT>
__global__ __launch_bounds__(256) void gemm_bt_k(const __hip_bfloat16* __restrict__ A,
                                                 const __hip_bfloat16* __restrict__ BT,
                                                 OutT* __restrict__ Cc,
                                                 int M, int N, int K) {
  __shared__ alignas(16) __hip_bfloat16 As[128 * 32];
  __shared__ alignas(16) __hip_bfloat16 Bs[128 * 32];
  const int tid = threadIdx.x;
  const int bm = blockIdx.y * 128;
  const int bn = blockIdx.x * 128;
  const int wave = tid >> 6, lane = tid & 63;
  const int wr = (wave >> 1) * 64, wc = (wave & 1) * 64;
  const int lm = lane & 15, lk = (lane >> 4) * 8;
  const size_t Kz = (size_t)K;
  const __hip_bfloat16* a0 = A + (size_t)(bm + (tid >> 2)) * Kz + (size_t)((tid & 3) * 8);
  const __hip_bfloat16* b0 = BT + (size_t)(bn + (tid >> 2)) * Kz + (size_t)((tid & 3) * 8);
  const __hip_bfloat16* a1 = a0 + 64 * Kz;
  const __hip_bfloat16* b1 = b0 + 64 * Kz;
  f32x4 acc[4][4] = {};
  for (int k0 = 0; k0 < K; k0 += 32) {
    async_copy16(a0 + k0, As + tid * 8);
    async_copy16(a1 + k0, As + 2048 + tid * 8);
    async_copy16(b0 + k0, Bs + tid * 8);
    async_copy16(b1 + k0, Bs + 2048 + tid * 8);
    __syncthreads();
    bf16x8 af[4], bfr[4];
    #pragma unroll
    for (int t = 0; t < 4; ++t) {
      af[t]  = *(const bf16x8*)(As + (wr + t * 16 + lm) * 32 + lk);
      bfr[t] = *(const bf16x8*)(Bs + (wc + t * 16 + lm) * 32 + lk);
    }
    #pragma unroll
    for (int mt = 0; mt < 4; ++mt)
      #pragma unroll
      for (int nt = 0; nt < 4; ++nt)
        acc[mt][nt] = __builtin_amdgcn_mfma_f32_16x16x32_bf16(af[mt], bfr[nt], acc[mt][nt], 0, 0, 0);
    __syncthreads();
  }
  const int r0 = (lane >> 4) * 4;
  #pragma unroll
  for (int mt = 0; mt < 4; ++mt)
    #pragma unroll
    for (int nt = 0; nt < 4; ++nt)
      #pragma unroll
      for (int r = 0; r < 4; ++r) {
        int gr = bm + wr + mt * 16 + r0 + r;
        int gc = bn + wc + nt * 16 + lm;
        float v = acc[mt][nt][r];
        if constexpr (__is_same(OutT, float))
          Cc[(size_t)gr * N + gc] = v;
        else
          Cc[(size_t)gr * N + gc] = __float2bfloat16(v);
      }
}

// ---------------- flash attention v2: swizzled LDS, transposed V, double-buffered K/V ----
// grid (T/64, NH, B); block 256 (4 waves, 16 q-rows each).
// q: [B][T][C] bf16 (l2-normed * 1/sqrt(HD)); kv: [B][T][1024] ([0:512]=k l2-normed);
// vt: [B*4][128][T] bf16 (V transposed).
__global__ __launch_bounds__(256) void attn_k(const __hip_bfloat16* __restrict__ q,
                                              const __hip_bfloat16* __restrict__ kv,
                                              const __hip_bfloat16* __restrict__ vt,
                                              __hip_bfloat16* __restrict__ y) {
  const int qt = (int)gridDim.x - 1 - (int)blockIdx.x;  // heavy blocks first
  const int h  = blockIdx.y;
  const int b  = blockIdx.z;
  const int g  = h >> 2;
  const int tid = threadIdx.x;
  const int wave = tid >> 6, lane = tid & 63;
  const int lm = lane & 15;
  const int quad = lane >> 4;
  const int r0 = quad * 4;

  // XOR-swizzled tiles: Q/K chunk (row,c) holds global chunk c^(row&15);
  // Vt chunk (row,c) holds global chunk c^(row&7). 16B chunks.
  __shared__ alignas(16) __hip_bfloat16 Qs[64 * 128];
  __shared__ alignas(16) __hip_bfloat16 Ks[2][64 * 128];
  __shared__ alignas(16) __hip_bfloat16 Vts[2][128 * 64];

  const __hip_bfloat16* qb = q + ((size_t)b * T_ + (size_t)qt * 64) * C_ + h * HD_;
  #pragma unroll
  for (int e = 0; e < 4; ++e) {
    int idx = tid + e * 256;
    int row = idx >> 4, c = idx & 15;
    async_copy16(qb + (size_t)row * C_ + ((c ^ (row & 15)) * 8), Qs + idx * 8);
  }
  const __hip_bfloat16* kb = kv + (size_t)b * T_ * KVD_ + g * HD_;
  const __hip_bfloat16* vb = vt + (size_t)(b * 4 + g) * HD_ * T_;
  #pragma unroll
  for (int e = 0; e < 4; ++e) {
    int idx = tid + e * 256;
    int row = idx >> 4, c = idx & 15;
    async_copy16(kb + (size_t)row * KVD_ + ((c ^ (row & 15)) * 8), Ks[0] + idx * 8);
  }
  #pragma unroll
  for (int e = 0; e < 4; ++e) {
    int idx = tid + e * 256;
    int row = idx >> 3, c = idx & 7;
    async_copy16(vb + (size_t)row * T_ + ((c ^ (row & 7)) * 8), Vts[0] + idx * 8);
  }
  __syncthreads();

  bf16x8 qf[4];
  #pragma unroll
  for (int kc = 0; kc < 4; ++kc)
    qf[kc] = *(const bf16x8*)(Qs + (wave * 16 + lm) * 128 + (((kc * 4 + quad) ^ lm) * 8));

  // P scratch: wave-private, inside this wave's own Q rows (qf already in regs).
  // 16 rows x stride 72 (144B, 16B-aligned, 4-dword bank shift) = 1152 el <= 2048.
  __hip_bfloat16* Psw = Qs + wave * 2048;

  float m_run[4] = {-1e30f, -1e30f, -1e30f, -1e30f};
  float l_run[4] = {0.f, 0.f, 0.f, 0.f};
  f32x4 o_acc[8] = {};

  const int ntiles = qt + 1;
  for (int it = 0; it < ntiles; ++it) {
    const int cur = it & 1;
    // prefetch next K/V tile into the other buffer (latency overlapped w/ compute)
    if (it + 1 < ntiles) {
      const int nxt = cur ^ 1;
      const int j1 = (it + 1) * 64;
      #pragma unroll
      for (int e = 0; e < 4; ++e) {
        int idx = tid + e * 256;
        int row = idx >> 4, c = idx & 15;
        async_copy16(kb + (size_t)(j1 + row) * KVD_ + ((c ^ (row & 15)) * 8), Ks[nxt] + idx * 8);
      }
      #pragma unroll
      for (int e = 0; e < 4; ++e) {
        int idx = tid + e * 256;
        int row = idx >> 3, c = idx & 7;
        async_copy16(vb + (size_t)row * T_ + j1 + ((c ^ (row & 7)) * 8), Vts[nxt] + idx * 8);
      }
    }
    // S = Q K^T (scale pre-folded into q)
    f32x4 sv[4] = {};
    #pragma unroll
    for (int kc = 0; kc < 4; ++kc) {
      #pragma unroll
      for (int st = 0; st < 4; ++st) {
        int row = st * 16 + lm;
        bf16x8 kf = *(const bf16x8*)(Ks[cur] + row * 128 + (((kc * 4 + quad) ^ lm) * 8));
        sv[st] = __builtin_amdgcn_mfma_f32_16x16x32_bf16(qf[kc], kf, sv[st], 0, 0, 0);
      }
    }
    const int j0 = it * 64;
    const int qg = qt * 64 + wave * 16 + r0;  // + r
    float mt_[4] = {-1e30f, -1e30f, -1e30f, -1e30f};
    #pragma unroll
    for (int st = 0; st < 4; ++st) {
      int sg = j0 + st * 16 + lm;
      #pragma unroll
      for (int r = 0; r < 4; ++r) {
        float s = sv[st][r];
        s = (sg > qg + r) ? -1e30f : s;
        sv[st][r] = s;
        mt_[r] = fmaxf(mt_[r], s);
      }
    }
    #pragma unroll
    for (int r = 0; r < 4; ++r) {
      #pragma unroll
      for (int off = 1; off <= 8; off <<= 1)
        mt_[r] = fmaxf(mt_[r], __shfl_xor(mt_[r], off, 64));
      float mn = fmaxf(m_run[r], mt_[r]);
      mt_[r] = __expf(m_run[r] - mn);  // alpha
      m_run[r] = mn;
    }
    float rs[4] = {0.f, 0.f, 0.f, 0.f};
    #pragma unroll
    for (int st = 0; st < 4; ++st)
      #pragma unroll
      for (int r = 0; r < 4; ++r) {
        float pv = __expf(sv[st][r] - m_run[r]);
        sv[st][r] = pv;
        rs[r] += pv;
      }
    #pragma unroll
    for (int r = 0; r < 4; ++r) {
      #pragma unroll
      for (int off = 1; off <= 8; off <<= 1)
        rs[r] += __shfl_xor(rs[r], off, 64);
      l_run[r] = l_run[r] * mt_[r] + rs[r];
    }
    #pragma unroll
    for (int nt = 0; nt < 8; ++nt)
      #pragma unroll
      for (int r = 0; r < 4; ++r)
        o_acc[nt][r] = o_acc[nt][r] * mt_[r];
    // P: C-layout -> A-layout via wave-private LDS round trip (stride 72)
    #pragma unroll
    for (int st = 0; st < 4; ++st)
      #pragma unroll
      for (int r = 0; r < 4; ++r)
        Psw[(r0 + r) * 72 + st * 16 + lm] = __float2bfloat16(sv[st][r]);
    __asm__ volatile("s_waitcnt lgkmcnt(0)" ::: "memory");
    // O += P V   (V B-frags from transposed-V tile, one b128 each)
    #pragma unroll
    for (int kc = 0; kc < 2; ++kc) {
      bf16x8 pf = *(const bf16x8*)(Psw + lm * 72 + kc * 32 + quad * 8);
      #pragma unroll
      for (int nt = 0; nt < 8; ++nt) {
        int row = nt * 16 + lm;
        bf16x8 vf = *(const bf16x8*)(Vts[cur] + row * 64 + (((kc * 4 + quad) ^ (row & 7)) * 8));
        o_acc[nt] = __builtin_amdgcn_mfma_f32_16x16x32_bf16(pf, vf, o_acc[nt], 0, 0, 0);
      }
    }
    __syncthreads();  // drains prefetch vmcnt + protects buffer swap
  }
  // epilogue: y[b][t][h*HD + d] = O / l
  #pragma unroll
  for (int nt = 0; nt < 8; ++nt)
    #pragma unroll
    for (int r = 0; r < 4; ++r) {
      int t = qt * 64 + wave * 16 + r0 + r;
      int d = nt * 16 + lm;
      float val = o_acc[nt][r] / l_run[r];
      y[((size_t)b * T_ + t) * C_ + h * HD_ + d] = __float2bfloat16(val);
    }
}

extern "C" void kernel_launch(void* const* d_in, const int* in_sizes, int n_in,
                              void* d_out, int out_size, void* d_ws, size_t ws_size,
                              hipStream_t stream) {
  (void)in_sizes; (void)n_in; (void)out_size; (void)ws_size;
  const float* x     = (const float*)d_in[0];
  const float* Wq    = (const float*)d_in[1];
  const float* Wkv   = (const float*)d_in[2];
  const float* Wproj = (const float*)d_in[3];
  char* ws = (char*)d_ws;
  __hip_bfloat16* xb     = (__hip_bfloat16*)(ws);               // 32 MB (reused as y)
  __hip_bfloat16* WqT    = (__hip_bfloat16*)(ws + 33554432);    //  8 MB
  __hip_bfloat16* WkvT   = (__hip_bfloat16*)(ws + 41943040);    //  4 MB
  __hip_bfloat16* WprojT = (__hip_bfloat16*)(ws + 46137344);    //  8 MB
  __hip_bfloat16* qn     = (__hip_bfloat16*)(ws + 54525952);    // 32 MB
  __hip_bfloat16* kvb    = (__hip_bfloat16*)(ws + 88080384);    // 16 MB
  __hip_bfloat16* y      = xb;                                  // alias: xb dead after kv-gemm
  __hip_bfloat16* vt     = (__hip_bfloat16*)d_out;              // 16 MB scratch in d_out (dead before final gemm)
  float* out             = (float*)d_out;

  f32_to_bf16_k<<<16384, 256, 0, stream>>>(x, xb, 4194304);
  transpose_f32_bf16_k<<<dim3(64, 64), dim3(32, 8), 0, stream>>>(Wq, WqT, 2048, 2048);
  transpose_f32_bf16_k<<<dim3(32, 64), dim3(32, 8), 0, stream>>>(Wkv, WkvT, 2048, 1024);
  transpose_f32_bf16_k<<<dim3(64, 64), dim3(32, 8), 0, stream>>>(Wproj, WprojT, 2048, 2048);
  gemm_bt_k<__hip_bfloat16><<<dim3(16, 64), 256, 0, stream>>>(xb, WqT, qn, 8192, 2048, 2048);
  gemm_bt_k<__hip_bfloat16><<<dim3(8, 64), 256, 0, stream>>>(xb, WkvT, kvb, 8192, 1024, 2048);
  rownorm_k<8><<<8192, 256, 0, stream>>>(qn, 2048, 0.08838834764831845f);  // 1/sqrt(HD) folded
  rownorm_k<2><<<8192, 256, 0, stream>>>(kvb, 1024, 1.0f);
  vtrans_k<<<dim3(64, 4, 16), dim3(32, 8), 0, stream>>>(kvb, vt);
  attn_k<<<dim3(32, 16, 4), 256, 0, stream>>>(qn, kvb, vt, y);
  gemm_bt_k<float><<<dim3(16, 64), 256, 0, stream>>>(y, WprojT, out, 8192, 2048, 2048);
}

// Round 4
// 650.273 us; speedup vs baseline: 1.6171x; 1.1753x over previous
//
#include <hip/hip_runtime.h>
#include <hip/hip_bf16.h>
#include <math.h>

#define B_   4
#define T_   2048
#define C_   2048
#define NH_  16
#define HD_  128
#define KVD_ 1024

typedef __attribute__((ext_vector_type(4))) float f32x4;
typedef __attribute__((ext_vector_type(8))) short bf16x8;

__device__ __forceinline__ void async_copy16(const __hip_bfloat16* g, __hip_bfloat16* l) {
  __builtin_amdgcn_global_load_lds((const __attribute__((address_space(1))) void*)g,
                                   (__attribute__((address_space(3))) void*)l,
                                   16, 0, 0);
}

__device__ __forceinline__ float bf2f(__hip_bfloat16 h) { return __bfloat162float(h); }

// ---------------- f32 -> bf16 convert (x) ----------------
__global__ __launch_bounds__(256) void f32_to_bf16_k(const float* __restrict__ src,
                                                     __hip_bfloat16* __restrict__ dst, int n4) {
  int i = blockIdx.x * 256 + threadIdx.x;
  if (i >= n4) return;
  float4 f = ((const float4*)src)[i];
  __hip_bfloat16 o[4] = {__float2bfloat16(f.x), __float2bfloat16(f.y),
                         __float2bfloat16(f.z), __float2bfloat16(f.w)};
  *(uint2*)(dst + (size_t)i * 4) = *(uint2*)o;
}

// ---------------- transpose + convert: WT[n][k] = bf16(W[k][n]) ----------------
__global__ __launch_bounds__(256) void transpose_f32_bf16_k(const float* __restrict__ W,
                                                            __hip_bfloat16* __restrict__ WT,
                                                            int K, int N) {
  __shared__ float tile[32][33];
  int bx = blockIdx.x * 32;  // n
  int by = blockIdx.y * 32;  // k
  int tx = threadIdx.x, ty = threadIdx.y;
  for (int i = ty; i < 32; i += 8)
    tile[i][tx] = W[(size_t)(by + i) * N + (bx + tx)];
  __syncthreads();
  for (int i = ty; i < 32; i += 8)
    WT[(size_t)(bx + i) * K + (by + tx)] = __float2bfloat16(tile[tx][i]);
}

// ---------------- V transpose: Vt[b][g][d][t] = kv[b][t][512 + g*128 + d] ----------------
__global__ __launch_bounds__(256) void vtrans_k(const __hip_bfloat16* __restrict__ kv,
                                                __hip_bfloat16* __restrict__ vt) {
  __shared__ __hip_bfloat16 tile[32][33];
  int bg = blockIdx.z;            // b*4+g
  int d0 = blockIdx.y * 32;
  int t0 = blockIdx.x * 32;
  int tx = threadIdx.x, ty = threadIdx.y;
  int b = bg >> 2, g = bg & 3;
  const __hip_bfloat16* src = kv + (size_t)b * T_ * KVD_ + 512 + g * HD_;
  for (int i = ty; i < 32; i += 8)
    tile[i][tx] = src[(size_t)(t0 + i) * KVD_ + d0 + tx];
  __syncthreads();
  __hip_bfloat16* dst = vt + (size_t)bg * HD_ * T_;
  for (int i = ty; i < 32; i += 8)
    dst[(size_t)(d0 + i) * T_ + t0 + tx] = tile[tx][i];
}

// ---------------- row l2norm (in place, bf16), scale folded via `extra` ----------------
template<int PER>
__global__ __launch_bounds__(256) void rownorm_k(__hip_bfloat16* __restrict__ buf,
                                                 int stride, float extra) {
  const int tid = threadIdx.x;
  __hip_bfloat16* p = buf + (size_t)blockIdx.x * stride;
  float v[PER];
  float ss = 0.f;
  #pragma unroll
  for (int e = 0; e < PER; ++e) { v[e] = bf2f(p[tid + e * 256]); ss += v[e] * v[e]; }
  #pragma unroll
  for (int off = 32; off >= 1; off >>= 1) ss += __shfl_xor(ss, off, 64);
  __shared__ float wsum[4];
  if ((tid & 63) == 0) wsum[tid >> 6] = ss;
  __syncthreads();
  float tot = wsum[0] + wsum[1] + wsum[2] + wsum[3];
  float sc = extra / (sqrtf(tot) + 1e-12f);
  #pragma unroll
  for (int e = 0; e < PER; ++e) p[tid + e * 256] = __float2bfloat16(v[e] * sc);
}

// ---------------- GEMM: C[M][N] = A[M][K] @ BT[N][K]^T, bf16 in, OutT out ----------------
template<typename OutT>
__global__ __launch_bounds__(256) void gemm_bt_k(const __hip_bfloat16* __restrict__ A,
                                                 const __hip_bfloat16* __restrict__ BT,
                                                 OutT* __restrict__ Cc,
                                                 int M, int N, int K) {
  __shared__ alignas(16) __hip_bfloat16 As[128 * 32];
  __shared__ alignas(16) __hip_bfloat16 Bs[128 * 32];
  const int tid = threadIdx.x;
  const int bm = blockIdx.y * 128;
  const int bn = blockIdx.x * 128;
  const int wave = tid >> 6, lane = tid & 63;
  const int wr = (wave >> 1) * 64, wc = (wave & 1) * 64;
  const int lm = lane & 15, lk = (lane >> 4) * 8;
  const size_t Kz = (size_t)K;
  const __hip_bfloat16* a0 = A + (size_t)(bm + (tid >> 2)) * Kz + (size_t)((tid & 3) * 8);
  const __hip_bfloat16* b0 = BT + (size_t)(bn + (tid >> 2)) * Kz + (size_t)((tid & 3) * 8);
  const __hip_bfloat16* a1 = a0 + 64 * Kz;
  const __hip_bfloat16* b1 = b0 + 64 * Kz;
  f32x4 acc[4][4] = {};
  for (int k0 = 0; k0 < K; k0 += 32) {
    async_copy16(a0 + k0, As + tid * 8);
    async_copy16(a1 + k0, As + 2048 + tid * 8);
    async_copy16(b0 + k0, Bs + tid * 8);
    async_copy16(b1 + k0, Bs + 2048 + tid * 8);
    __syncthreads();
    bf16x8 af[4], bfr[4];
    #pragma unroll
    for (int t = 0; t < 4; ++t) {
      af[t]  = *(const bf16x8*)(As + (wr + t * 16 + lm) * 32 + lk);
      bfr[t] = *(const bf16x8*)(Bs + (wc + t * 16 + lm) * 32 + lk);
    }
    #pragma unroll
    for (int mt = 0; mt < 4; ++mt)
      #pragma unroll
      for (int nt = 0; nt < 4; ++nt)
        acc[mt][nt] = __builtin_amdgcn_mfma_f32_16x16x32_bf16(af[mt], bfr[nt], acc[mt][nt], 0, 0, 0);
    __syncthreads();
  }
  const int r0 = (lane >> 4) * 4;
  #pragma unroll
  for (int mt = 0; mt < 4; ++mt)
    #pragma unroll
    for (int nt = 0; nt < 4; ++nt)
      #pragma unroll
      for (int r = 0; r < 4; ++r) {
        int gr = bm + wr + mt * 16 + r0 + r;
        int gc = bn + wc + nt * 16 + lm;
        float v = acc[mt][nt][r];
        if constexpr (__is_same(OutT, float))
          Cc[(size_t)gr * N + gc] = v;
        else
          Cc[(size_t)gr * N + gc] = __float2bfloat16(v);
      }
}

// ---------------- flash attention v3: fixed-max softmax (scores bounded) ----------------
// q l2-normed over full row & k l2-normed => |score| <= 1/sqrt(128) = 0.0884.
// exp never overflows -> no running max, no alpha rescale, no per-iter reductions.
// grid (T/64, NH, B); block 256 (4 waves, 16 q-rows each).
__global__ __launch_bounds__(256) void attn_k(const __hip_bfloat16* __restrict__ q,
                                              const __hip_bfloat16* __restrict__ kv,
                                              const __hip_bfloat16* __restrict__ vt,
                                              __hip_bfloat16* __restrict__ y) {
  const int qt = (int)gridDim.x - 1 - (int)blockIdx.x;  // heavy blocks first
  const int h  = blockIdx.y;
  const int b  = blockIdx.z;
  const int g  = h >> 2;
  const int tid = threadIdx.x;
  const int wave = tid >> 6, lane = tid & 63;
  const int lm = lane & 15;
  const int quad = lane >> 4;
  const int r0 = quad * 4;

  // XOR-swizzled tiles: Q/K chunk (row,c) holds global chunk c^(row&15);
  // Vt chunk (row,c) holds global chunk c^(row&7). 16B chunks.
  __shared__ alignas(16) __hip_bfloat16 Qs[64 * 128];
  __shared__ alignas(16) __hip_bfloat16 Ks[2][64 * 128];
  __shared__ alignas(16) __hip_bfloat16 Vts[2][128 * 64];

  const __hip_bfloat16* qb = q + ((size_t)b * T_ + (size_t)qt * 64) * C_ + h * HD_;
  #pragma unroll
  for (int e = 0; e < 4; ++e) {
    int idx = tid + e * 256;
    int row = idx >> 4, c = idx & 15;
    async_copy16(qb + (size_t)row * C_ + ((c ^ (row & 15)) * 8), Qs + idx * 8);
  }
  const __hip_bfloat16* kb = kv + (size_t)b * T_ * KVD_ + g * HD_;
  const __hip_bfloat16* vb = vt + (size_t)(b * 4 + g) * HD_ * T_;
  #pragma unroll
  for (int e = 0; e < 4; ++e) {
    int idx = tid + e * 256;
    int row = idx >> 4, c = idx & 15;
    async_copy16(kb + (size_t)row * KVD_ + ((c ^ (row & 15)) * 8), Ks[0] + idx * 8);
  }
  #pragma unroll
  for (int e = 0; e < 4; ++e) {
    int idx = tid + e * 256;
    int row = idx >> 3, c = idx & 7;
    async_copy16(vb + (size_t)row * T_ + ((c ^ (row & 7)) * 8), Vts[0] + idx * 8);
  }
  __syncthreads();

  bf16x8 qf[4];
  #pragma unroll
  for (int kc = 0; kc < 4; ++kc)
    qf[kc] = *(const bf16x8*)(Qs + (wave * 16 + lm) * 128 + (((kc * 4 + quad) ^ lm) * 8));

  // P scratch: wave-private, inside this wave's own Q rows (qf already in regs).
  // 16 rows x stride 72 (144B, 16B-aligned, 4-dword bank shift) = 1152 el <= 2048.
  __hip_bfloat16* Psw = Qs + wave * 2048;

  float l_acc[4] = {0.f, 0.f, 0.f, 0.f};  // per-lane partial row sums (reduced once at end)
  f32x4 o_acc[8] = {};

  const int ntiles = qt + 1;
  for (int it = 0; it < ntiles; ++it) {
    const int cur = it & 1;
    // prefetch next K/V tile into the other buffer (latency overlapped w/ compute)
    if (it + 1 < ntiles) {
      const int nxt = cur ^ 1;
      const int j1 = (it + 1) * 64;
      #pragma unroll
      for (int e = 0; e < 4; ++e) {
        int idx = tid + e * 256;
        int row = idx >> 4, c = idx & 15;
        async_copy16(kb + (size_t)(j1 + row) * KVD_ + ((c ^ (row & 15)) * 8), Ks[nxt] + idx * 8);
      }
      #pragma unroll
      for (int e = 0; e < 4; ++e) {
        int idx = tid + e * 256;
        int row = idx >> 3, c = idx & 7;
        async_copy16(vb + (size_t)row * T_ + j1 + ((c ^ (row & 7)) * 8), Vts[nxt] + idx * 8);
      }
    }
    // S = Q K^T (scale pre-folded into q)
    f32x4 sv[4] = {};
    #pragma unroll
    for (int kc = 0; kc < 4; ++kc) {
      #pragma unroll
      for (int st = 0; st < 4; ++st) {
        int row = st * 16 + lm;
        bf16x8 kf = *(const bf16x8*)(Ks[cur] + row * 128 + (((kc * 4 + quad) ^ lm) * 8));
        sv[st] = __builtin_amdgcn_mfma_f32_16x16x32_bf16(qf[kc], kf, sv[st], 0, 0, 0);
      }
    }
    // P = exp(S) with causal mask (no max subtraction needed: |S| <= 0.0884)
    const int j0 = it * 64;
    const int qg = qt * 64 + wave * 16 + r0;  // + r
    #pragma unroll
    for (int st = 0; st < 4; ++st) {
      int sg = j0 + st * 16 + lm;
      #pragma unroll
      for (int r = 0; r < 4; ++r) {
        float pv = (sg > qg + r) ? 0.f : __expf(sv[st][r]);
        sv[st][r] = pv;
        l_acc[r] += pv;
      }
    }
    // P: C-layout -> A-layout via wave-private LDS round trip (stride 72)
    #pragma unroll
    for (int st = 0; st < 4; ++st)
      #pragma unroll
      for (int r = 0; r < 4; ++r)
        Psw[(r0 + r) * 72 + st * 16 + lm] = __float2bfloat16(sv[st][r]);
    __asm__ volatile("s_waitcnt lgkmcnt(0)" ::: "memory");
    // O += P V   (V B-frags from transposed-V tile, one b128 each)
    #pragma unroll
    for (int kc = 0; kc < 2; ++kc) {
      bf16x8 pf = *(const bf16x8*)(Psw + lm * 72 + kc * 32 + quad * 8);
      #pragma unroll
      for (int nt = 0; nt < 8; ++nt) {
        int row = nt * 16 + lm;
        bf16x8 vf = *(const bf16x8*)(Vts[cur] + row * 64 + (((kc * 4 + quad) ^ (row & 7)) * 8));
        o_acc[nt] = __builtin_amdgcn_mfma_f32_16x16x32_bf16(pf, vf, o_acc[nt], 0, 0, 0);
      }
    }
    __syncthreads();  // drains prefetch vmcnt + protects buffer swap
  }
  // one-time row-sum reduce across the 16 lanes of each quad
  #pragma unroll
  for (int r = 0; r < 4; ++r)
    #pragma unroll
    for (int off = 1; off <= 8; off <<= 1)
      l_acc[r] += __shfl_xor(l_acc[r], off, 64);
  // epilogue: y[b][t][h*HD + d] = O / l
  #pragma unroll
  for (int nt = 0; nt < 8; ++nt)
    #pragma unroll
    for (int r = 0; r < 4; ++r) {
      int t = qt * 64 + wave * 16 + r0 + r;
      int d = nt * 16 + lm;
      float val = o_acc[nt][r] / l_acc[r];
      y[((size_t)b * T_ + t) * C_ + h * HD_ + d] = __float2bfloat16(val);
    }
}

extern "C" void kernel_launch(void* const* d_in, const int* in_sizes, int n_in,
                              void* d_out, int out_size, void* d_ws, size_t ws_size,
                              hipStream_t stream) {
  (void)in_sizes; (void)n_in; (void)out_size; (void)ws_size;
  const float* x     = (const float*)d_in[0];
  const float* Wq    = (const float*)d_in[1];
  const float* Wkv   = (const float*)d_in[2];
  const float* Wproj = (const float*)d_in[3];
  char* ws = (char*)d_ws;
  __hip_bfloat16* xb     = (__hip_bfloat16*)(ws);               // 32 MB (reused as y)
  __hip_bfloat16* WqT    = (__hip_bfloat16*)(ws + 33554432);    //  8 MB
  __hip_bfloat16* WkvT   = (__hip_bfloat16*)(ws + 41943040);    //  4 MB
  __hip_bfloat16* WprojT = (__hip_bfloat16*)(ws + 46137344);    //  8 MB
  __hip_bfloat16* qn     = (__hip_bfloat16*)(ws + 54525952);    // 32 MB
  __hip_bfloat16* kvb    = (__hip_bfloat16*)(ws + 88080384);    // 16 MB
  __hip_bfloat16* y      = xb;                                  // alias: xb dead after kv-gemm
  __hip_bfloat16* vt     = (__hip_bfloat16*)d_out;              // 16 MB scratch in d_out (dead before final gemm)
  float* out             = (float*)d_out;

  f32_to_bf16_k<<<16384, 256, 0, stream>>>(x, xb, 4194304);
  transpose_f32_bf16_k<<<dim3(64, 64), dim3(32, 8), 0, stream>>>(Wq, WqT, 2048, 2048);
  transpose_f32_bf16_k<<<dim3(32, 64), dim3(32, 8), 0, stream>>>(Wkv, WkvT, 2048, 1024);
  transpose_f32_bf16_k<<<dim3(64, 64), dim3(32, 8), 0, stream>>>(Wproj, WprojT, 2048, 2048);
  gemm_bt_k<__hip_bfloat16><<<dim3(16, 64), 256, 0, stream>>>(xb, WqT, qn, 8192, 2048, 2048);
  gemm_bt_k<__hip_bfloat16><<<dim3(8, 64), 256, 0, stream>>>(xb, WkvT, kvb, 8192, 1024, 2048);
  rownorm_k<8><<<8192, 256, 0, stream>>>(qn, 2048, 0.08838834764831845f);  // 1/sqrt(HD) folded
  rownorm_k<2><<<8192, 256, 0, stream>>>(kvb, 1024, 1.0f);
  vtrans_k<<<dim3(64, 4, 16), dim3(32, 8), 0, stream>>>(kvb, vt);
  attn_k<<<dim3(32, 16, 4), 256, 0, stream>>>(qn, kvb, vt, y);
  gemm_bt_k<float><<<dim3(16, 64), 256, 0, stream>>>(y, WprojT, out, 8192, 2048, 2048);
}